// Round 4
// baseline (495.115 us; speedup 1.0000x reference)
//
#include <hip/hip_runtime.h>
#include <math.h>

#define NN      8192
#define DIM     512      // IN_DIM == H*HID
#define NHEAD   8
#define HID     64
#define NE      262144
#define NE_HALF 131072
#define CMASK   (NE_HALF - 1)      // canonical edge id = j & CMASK (graph symmetric)
#define TOPK    10
#define NEGV    -9e15f
#define MAXD    160     // full-degree cap; true max deg ~60 (Binom mean 32)
#define MAXC    64      // canonical-degree cap; true max ~45 (Binom mean 16)

typedef __attribute__((ext_vector_type(8))) short short8;
typedef __attribute__((ext_vector_type(4))) float f32x4;
typedef __attribute__((ext_vector_type(2))) int i32x2;
typedef __attribute__((ext_vector_type(4))) int i32x4;

__device__ __forceinline__ float bf2f(unsigned int h) {
    return __uint_as_float(h << 16);
}
__device__ __forceinline__ unsigned short f2bf(float x) {
    unsigned int u = __float_as_uint(x);
    unsigned int r = (u + 0x7fff + ((u >> 16) & 1)) >> 16;   // RNE
    return (unsigned short)r;
}

// per-wave barrier: conv_body's LDS arrays are [4][...] wave-private slices.
// s_waitcnt lgkmcnt(0) guarantees all this wave's LDS writes retired before
// subsequent reads; wave_barrier pins compiler ordering. (verified passing R3)
__device__ __forceinline__ void wavebar() {
    asm volatile("s_waitcnt lgkmcnt(0)" ::: "memory");
    __builtin_amdgcn_wave_barrier();
}

// ---------------- scatter body (fused into c=0 gemm dispatch) --------------
// fixed-stride buckets: atomicAdd result IS the degree count (no scan needed)
__device__ __forceinline__ void scatter_body(int j, int c,
                                             const int* __restrict__ src0,
                                             const int* __restrict__ src1,
                                             const int* __restrict__ dst0,
                                             const int* __restrict__ dst1,
                                             const float* __restrict__ trans0,
                                             const float* __restrict__ trans1,
                                             int* curF, int* curC,
                                             i32x2* __restrict__ ed,
                                             i32x4* __restrict__ ce) {
    const int* s = c ? src1 : src0;
    const int* dt = c ? dst1 : dst0;
    int v = s[j];
    int dv = dt[j];
    int p = atomicAdd(&curF[c * NN + v], 1);
    if (p < MAXD) {
        i32x2 pk; pk.x = j; pk.y = dv;
        ed[(size_t)(c * NN + v) * MAXD + p] = pk;
    }
    if (j < NE_HALF) {
        const float* tr = c ? trans1 : trans0;
        int q = atomicAdd(&curC[c * NN + v], 1);
        if (q < MAXC) {
            i32x4 ck;
            ck.x = j; ck.y = dv; ck.z = __float_as_int(tr[j]); ck.w = 0;
            ce[(size_t)(c * NN + v) * MAXC + q] = ck;
        }
    }
}

// ---------------- GEMM body (shared: 24 KB LDS inside) ---------------------
__device__ __forceinline__ void gemm_body(int b,
                                          const unsigned short* __restrict__ Ah,
                                          const unsigned short* __restrict__ Al,
                                          const unsigned short* __restrict__ Bh,
                                          const unsigned short* __restrict__ Bl,
                                          float* __restrict__ Cf,
                                          unsigned short* __restrict__ Ch) {
    __shared__ unsigned short Ash[128][32];   // 8 KB
    __shared__ unsigned short Asl[128][32];   // 8 KB
    __shared__ unsigned short Bsh[64][32];    // 4 KB
    __shared__ unsigned short Bsl[64][32];    // 4 KB
    const int bm = (b >> 3) * 128;
    const int bn = (b & 7) * 64;
    const int tid = threadIdx.x;
    const int lane = tid & 63;
    const int wave = tid >> 6;
    const int wm = (wave >> 1) * 64, wn = (wave & 1) * 32;
    const int fr = lane & 15, fq = lane >> 4;
    const int sr = tid >> 2, sc = (tid & 3) * 8;
    f32x4 acc[4][2] = {};
    const unsigned short* Ahg = Ah + (size_t)(bm + sr) * DIM + sc;
    const unsigned short* Alg = Al + (size_t)(bm + sr) * DIM + sc;
    const unsigned short* Bhg = Bh + (size_t)(bn + sr) * DIM + sc;   // sr<64 rows used
    const unsigned short* Blg = Bl + (size_t)(bn + sr) * DIM + sc;
    for (int kb = 0; kb < DIM; kb += 32) {
        __syncthreads();
        __builtin_amdgcn_global_load_lds(
            (const __attribute__((address_space(1))) void*)(Ahg + kb),
            (__attribute__((address_space(3))) void*)(&Ash[sr][sc]), 16, 0, 0);
        __builtin_amdgcn_global_load_lds(
            (const __attribute__((address_space(1))) void*)(Ahg + (size_t)64 * DIM + kb),
            (__attribute__((address_space(3))) void*)(&Ash[sr + 64][sc]), 16, 0, 0);
        __builtin_amdgcn_global_load_lds(
            (const __attribute__((address_space(1))) void*)(Alg + kb),
            (__attribute__((address_space(3))) void*)(&Asl[sr][sc]), 16, 0, 0);
        __builtin_amdgcn_global_load_lds(
            (const __attribute__((address_space(1))) void*)(Alg + (size_t)64 * DIM + kb),
            (__attribute__((address_space(3))) void*)(&Asl[sr + 64][sc]), 16, 0, 0);
        if (sr < 64) {
            __builtin_amdgcn_global_load_lds(
                (const __attribute__((address_space(1))) void*)(Bhg + kb),
                (__attribute__((address_space(3))) void*)(&Bsh[sr][sc]), 16, 0, 0);
            __builtin_amdgcn_global_load_lds(
                (const __attribute__((address_space(1))) void*)(Blg + kb),
                (__attribute__((address_space(3))) void*)(&Bsl[sr][sc]), 16, 0, 0);
        }
        __syncthreads();
        short8 ah[4], al[4], bh[2], bl[2];
        #pragma unroll
        for (int i = 0; i < 4; i++) {
            ah[i] = *(const short8*)&Ash[wm + i * 16 + fr][fq * 8];
            al[i] = *(const short8*)&Asl[wm + i * 16 + fr][fq * 8];
        }
        #pragma unroll
        for (int i = 0; i < 2; i++) {
            bh[i] = *(const short8*)&Bsh[wn + i * 16 + fr][fq * 8];
            bl[i] = *(const short8*)&Bsl[wn + i * 16 + fr][fq * 8];
        }
        #pragma unroll
        for (int mi = 0; mi < 4; mi++)
            #pragma unroll
            for (int ni = 0; ni < 2; ni++) {
                acc[mi][ni] = __builtin_amdgcn_mfma_f32_16x16x32_bf16(ah[mi], bh[ni], acc[mi][ni], 0, 0, 0);
                acc[mi][ni] = __builtin_amdgcn_mfma_f32_16x16x32_bf16(al[mi], bh[ni], acc[mi][ni], 0, 0, 0);
                acc[mi][ni] = __builtin_amdgcn_mfma_f32_16x16x32_bf16(ah[mi], bl[ni], acc[mi][ni], 0, 0, 0);
            }
    }
    #pragma unroll
    for (int mi = 0; mi < 4; mi++)
        #pragma unroll
        for (int ni = 0; ni < 2; ni++)
            #pragma unroll
            for (int r = 0; r < 4; r++) {
                int row = bm + wm + mi * 16 + fq * 4 + r;
                int col = bn + wn + ni * 16 + fr;
                float v = acc[mi][ni][r];
                size_t off = (size_t)row * DIM + col;
                Cf[off] = v;
                Ch[off] = f2bf(v);
            }
}

// ---------------- edge-dots body (no LDS, 4 edges in flight per wave) ------
__device__ __forceinline__ void edge_body(int n,
                                          const float* __restrict__ Cf,
                                          const int* __restrict__ cdeg,
                                          const i32x4* __restrict__ ce,
                                          float* __restrict__ e,
                                          float* __restrict__ vals) {
    int d = cdeg[n];
    if (d > MAXC) d = MAXC;
    if (d <= 0) return;
    int wave = threadIdx.x >> 6, lane = threadIdx.x & 63;
    const float4* pf = (const float4*)(Cf + (size_t)n * DIM);
    float4 f0 = pf[lane * 2], f1 = pf[lane * 2 + 1];
    const size_t s0 = (size_t)n * MAXC;
    for (int base = wave * 4; base < d; base += 16) {
        int em = d - base; if (em > 4) em = 4;
        i32x4 c[4];
        #pragma unroll
        for (int t = 0; t < 4; t++)
            c[t] = ce[s0 + base + (t < em ? t : 0)];
        float4 b0[4], b1[4];
        #pragma unroll
        for (int t = 0; t < 4; t++) {
            const float4* q = (const float4*)(Cf + (size_t)c[t].y * DIM);
            b0[t] = q[lane * 2];
            b1[t] = q[lane * 2 + 1];
        }
        float p[4];
        #pragma unroll
        for (int t = 0; t < 4; t++) {
            p[t]  = f0.x * b0[t].x + f0.y * b0[t].y + f0.z * b0[t].z + f0.w * b0[t].w;
            p[t] += f1.x * b1[t].x + f1.y * b1[t].y + f1.z * b1[t].z + f1.w * b1[t].w;
            p[t] += __shfl_xor(p[t], 1);
            p[t] += __shfl_xor(p[t], 2);
            p[t] += __shfl_xor(p[t], 4);
        }
        if ((lane & 7) == 0) {
            int h = lane >> 3;
            #pragma unroll
            for (int t = 0; t < 4; t++)
                if (t < em) e[(size_t)c[t].x * NHEAD + h] = p[t];
        }
        #pragma unroll
        for (int t = 0; t < 4; t++) {
            p[t] += __shfl_xor(p[t], 8);
            p[t] += __shfl_xor(p[t], 16);
            p[t] += __shfl_xor(p[t], 32);
        }
        if (lane == 0) {
            #pragma unroll
            for (int t = 0; t < 4; t++)
                if (t < em) vals[c[t].x] = __int_as_float(c[t].z) * p[t];
        }
    }
}

// ---------------- conv-post body (wave-per-node, ~13 KB LDS) ---------------
// all LDS arrays are [4][...] wave-private slices -> wave-level barriers
// suffice (no cross-wave sharing); decouples the 4 waves' phase progress.
__device__ __forceinline__ void conv_body(int blk,
                                          const int* __restrict__ deg,
                                          const i32x2* __restrict__ ed,
                                          const float* __restrict__ e,
                                          const float* __restrict__ vals,
                                          const unsigned short* __restrict__ fb,
                                          unsigned short* __restrict__ zb) {
    const int tid = threadIdx.x;
    const int w = tid >> 6, lane = tid & 63;
    const int n = blk * 4 + w;
    int d = deg[n];
    if (d > MAXD) d = MAXD;
    const size_t s0 = (size_t)n * MAXD;
    __shared__ int   ssrc[4][MAXD];
    __shared__ int   sjc[4][MAXD];
    __shared__ float sval[4][MAXD];
    __shared__ float svc[4][MAXD];
    __shared__ unsigned char lead[4][MAXD];
    __shared__ short sk[4][MAXD];
    __shared__ float sms[4][2][NHEAD];
    __shared__ int nkept[4];

    for (int i = lane; i < d; i += 64) {
        i32x2 pk = ed[s0 + i];
        int jc = pk.x & CMASK;
        sjc[w][i] = jc;
        ssrc[w][i] = pk.y;
        sval[w][i] = vals[jc];
    }
    wavebar();
    for (int i = lane; i < d; i += 64) {
        int c = ssrc[w][i];
        float sum = 0.f;
        bool leader = true;
        for (int k = 0; k < d; k++) {
            if (ssrc[w][k] == c) {
                sum += sval[w][k];
                if (k < i) leader = false;
            }
        }
        svc[w][i] = sum;
        lead[w][i] = leader ? 1 : 0;
    }
    wavebar();
    {
        float v[3];
        #pragma unroll
        for (int s = 0; s < 3; s++) v[s] = -1.f;
        int cnt = 0;
        #pragma unroll
        for (int s = 0; s < 3; s++) {
            int i = lane + s * 64;
            if (i < d && lead[w][i] && svc[w][i] > 0.f) { v[s] = svc[w][i]; cnt++; }
        }
        cnt += __shfl_xor(cnt, 1);  cnt += __shfl_xor(cnt, 2);
        cnt += __shfl_xor(cnt, 4);  cnt += __shfl_xor(cnt, 8);
        cnt += __shfl_xor(cnt, 16); cnt += __shfl_xor(cnt, 32);
        float thr = 0.f;
        if (cnt >= TOPK) {
            unsigned long long key = 0;
            for (int t = 0; t < TOPK; t++) {
                unsigned int bb = 0; int bs = 0;
                #pragma unroll
                for (int s = 0; s < 3; s++) {
                    if (v[s] > 0.f) {
                        unsigned int b = __float_as_uint(v[s]);
                        if (b > bb) { bb = b; bs = s; }
                    }
                }
                key = ((unsigned long long)bb << 12) | (unsigned)(lane << 3) | (unsigned)bs;
                unsigned long long o;
                o = __shfl_xor(key, 1);  if (o > key) key = o;
                o = __shfl_xor(key, 2);  if (o > key) key = o;
                o = __shfl_xor(key, 4);  if (o > key) key = o;
                o = __shfl_xor(key, 8);  if (o > key) key = o;
                o = __shfl_xor(key, 16); if (o > key) key = o;
                o = __shfl_xor(key, 32); if (o > key) key = o;
                int owner = (int)((key >> 3) & 63);
                if (owner == lane) v[key & 7] = -1.f;   // remove one instance
            }
            thr = __uint_as_float((unsigned int)(key >> 12));
        }
        int base = 0;
        for (int s = 0; s * 64 < d; s++) {
            int i = s * 64 + lane;
            bool kp = (i < d) && (svc[w][i] >= thr);
            unsigned long long m = __ballot(kp);
            int pos = base + __popcll(m & ((1ull << lane) - 1ull));
            if (kp) sk[w][pos] = (short)i;
            base += (int)__popcll(m);
        }
        if (base == 0) {                 // all masked -> uniform over all d
            for (int i = lane; i < d; i += 64) sk[w][i] = (short)i;
            if (lane == 0) nkept[w] = -d;
        } else if (lane == 0) nkept[w] = base;
    }
    wavebar();
    int nk = nkept[w];
    nk = __shfl(nk, 0);   // wave-uniform broadcast (nkept written by lane 0)
    bool uni = nk < 0;
    int dk = uni ? -nk : nk;
    if (!uni) {
        int h = lane & 7, sub = lane >> 3;
        float m = -INFINITY;
        for (int k = sub; k < dk; k += 8)
            m = fmaxf(m, e[(size_t)sjc[w][sk[w][k]] * NHEAD + h]);
        m = fmaxf(m, __shfl_xor(m, 8));
        m = fmaxf(m, __shfl_xor(m, 16));
        m = fmaxf(m, __shfl_xor(m, 32));
        float s = 0.f;
        for (int k = sub; k < dk; k += 8)
            s += expf(e[(size_t)sjc[w][sk[w][k]] * NHEAD + h] - m);
        s += __shfl_xor(s, 8);
        s += __shfl_xor(s, 16);
        s += __shfl_xor(s, 32);
        if (sub == 0) { sms[w][0][h] = m; sms[w][1][h] = 1.0f / s; }
    }
    wavebar();
    int c0 = lane * 8;
    int h = lane >> 3;
    float a0 = 0.f, a1 = 0.f, a2 = 0.f, a3 = 0.f;
    float a4 = 0.f, a5 = 0.f, a6 = 0.f, a7 = 0.f;
    if (uni) {
        for (int k = 0; k < dk; k++) {
            int ii = sk[w][k];
            uint4 v = *(const uint4*)(fb + (size_t)ssrc[w][ii] * DIM + c0);
            a0 += bf2f(v.x & 0xffffu); a1 += bf2f(v.x >> 16);
            a2 += bf2f(v.y & 0xffffu); a3 += bf2f(v.y >> 16);
            a4 += bf2f(v.z & 0xffffu); a5 += bf2f(v.z >> 16);
            a6 += bf2f(v.w & 0xffffu); a7 += bf2f(v.w >> 16);
        }
        float invd = 1.0f / (float)d;
        a0 *= invd; a1 *= invd; a2 *= invd; a3 *= invd;
        a4 *= invd; a5 *= invd; a6 *= invd; a7 *= invd;
    } else {
        float m_h = sms[w][0][h], is_h = sms[w][1][h];
        for (int kb = 0; kb < dk; kb += 8) {
            int rem = dk - kb; if (rem > 8) rem = 8;
            // one expf per lane covers (edge kb+(lane&7), head lane>>3)
            float wv = 0.f;
            {
                int t = lane & 7;
                if (t < rem) {
                    int ii = sk[w][kb + t];
                    wv = expf(e[(size_t)sjc[w][ii] * NHEAD + h] - m_h) * is_h;
                }
            }
#define AGG(j) { \
            float wgt = __shfl(wv, (lane & 56) | (j)); \
            int ii2 = sk[w][kb + (j)]; \
            uint4 vv = *(const uint4*)(fb + (size_t)ssrc[w][ii2] * DIM + c0); \
            a0 += wgt * bf2f(vv.x & 0xffffu); a1 += wgt * bf2f(vv.x >> 16); \
            a2 += wgt * bf2f(vv.y & 0xffffu); a3 += wgt * bf2f(vv.y >> 16); \
            a4 += wgt * bf2f(vv.z & 0xffffu); a5 += wgt * bf2f(vv.z >> 16); \
            a6 += wgt * bf2f(vv.w & 0xffffu); a7 += wgt * bf2f(vv.w >> 16); }
            if (rem == 8) {
                AGG(0) AGG(1) AGG(2) AGG(3) AGG(4) AGG(5) AGG(6) AGG(7)
            } else {
                for (int j = 0; j < rem; j++) AGG(j)
            }
#undef AGG
        }
    }
    a0 = a0 > 0.f ? a0 : expf(a0) - 1.f;
    a1 = a1 > 0.f ? a1 : expf(a1) - 1.f;
    a2 = a2 > 0.f ? a2 : expf(a2) - 1.f;
    a3 = a3 > 0.f ? a3 : expf(a3) - 1.f;
    a4 = a4 > 0.f ? a4 : expf(a4) - 1.f;
    a5 = a5 > 0.f ? a5 : expf(a5) - 1.f;
    a6 = a6 > 0.f ? a6 : expf(a6) - 1.f;
    a7 = a7 > 0.f ? a7 : expf(a7) - 1.f;
    uint4 o;
    o.x = (unsigned)f2bf(a0) | ((unsigned)f2bf(a1) << 16);
    o.y = (unsigned)f2bf(a2) | ((unsigned)f2bf(a3) << 16);
    o.z = (unsigned)f2bf(a4) | ((unsigned)f2bf(a5) << 16);
    o.w = (unsigned)f2bf(a6) | ((unsigned)f2bf(a7) << 16);
    *(uint4*)(zb + (size_t)n * DIM + c0) = o;
}

// ---------------- lin body: y[n][o] = z[n] @ lin_w (wave per node) ---------
__device__ __forceinline__ void lin_body(int blk,
                                         const unsigned short* __restrict__ zb,
                                         const float* __restrict__ lin_w,
                                         float* __restrict__ y) {
    int tid = threadIdx.x;
    int w = tid >> 6, lane = tid & 63;
    int n = blk * 4 + w;
    uint4 v = *(const uint4*)(zb + (size_t)n * DIM + lane * 8);
    float f[8];
    f[0] = bf2f(v.x & 0xffffu); f[1] = bf2f(v.x >> 16);
    f[2] = bf2f(v.y & 0xffffu); f[3] = bf2f(v.y >> 16);
    f[4] = bf2f(v.z & 0xffffu); f[5] = bf2f(v.z >> 16);
    f[6] = bf2f(v.w & 0xffffu); f[7] = bf2f(v.w >> 16);
    // lin_w rows for dims [lane*8, lane*8+8): 24 contiguous floats = 6 float4
    float lwv[24];
    #pragma unroll
    for (int q = 0; q < 6; q++)
        *(float4*)&lwv[q * 4] = ((const float4*)lin_w)[lane * 6 + q];
    float acc0 = 0.f, acc1 = 0.f, acc2 = 0.f;
    #pragma unroll
    for (int j = 0; j < 8; j++) {
        acc0 += f[j] * lwv[j * 3 + 0];
        acc1 += f[j] * lwv[j * 3 + 1];
        acc2 += f[j] * lwv[j * 3 + 2];
    }
    #pragma unroll
    for (int s = 1; s < 64; s <<= 1) {
        acc0 += __shfl_xor(acc0, s);
        acc1 += __shfl_xor(acc1, s);
        acc2 += __shfl_xor(acc2, s);
    }
    if (lane == 0) {
        y[n * 3 + 0] = acc0;
        y[n * 3 + 1] = acc1;
        y[n * 3 + 2] = acc2;
    }
}

// ---------------- semantic attention scores (MFMA, fused tanh epilogue) -----
__device__ __forceinline__ void sem_body(int bx,
                                         const unsigned short* __restrict__ Z,
                                         const unsigned short* __restrict__ W1hT,
                                         const unsigned short* __restrict__ W1lT,
                                         const float* __restrict__ b1,
                                         const float* __restrict__ w2,
                                         float* wsum_slot) {
    const int bm = bx * 64;
    const int tid = threadIdx.x;
    const int lane = tid & 63, wave = tid >> 6;
    const int fr = lane & 15, fq = lane >> 4;
    __shared__ unsigned short Zs[64][32];     // 4 KB
    __shared__ unsigned short Wh[128][32];    // 8 KB
    __shared__ unsigned short Wl[128][32];    // 8 KB
    const int sr = tid >> 2, sc = (tid & 3) * 8;
    f32x4 acc[8] = {};
    const unsigned short* Zg  = Z    + (size_t)(bm + sr) * DIM + sc;
    const unsigned short* Whg = W1hT + (size_t)sr * DIM + sc;
    const unsigned short* Wlg = W1lT + (size_t)sr * DIM + sc;
    for (int kb = 0; kb < DIM; kb += 32) {
        __syncthreads();
        __builtin_amdgcn_global_load_lds(
            (const __attribute__((address_space(1))) void*)(Zg + kb),
            (__attribute__((address_space(3))) void*)(&Zs[sr][sc]), 16, 0, 0);
        __builtin_amdgcn_global_load_lds(
            (const __attribute__((address_space(1))) void*)(Whg + kb),
            (__attribute__((address_space(3))) void*)(&Wh[sr][sc]), 16, 0, 0);
        __builtin_amdgcn_global_load_lds(
            (const __attribute__((address_space(1))) void*)(Whg + (size_t)64 * DIM + kb),
            (__attribute__((address_space(3))) void*)(&Wh[sr + 64][sc]), 16, 0, 0);
        __builtin_amdgcn_global_load_lds(
            (const __attribute__((address_space(1))) void*)(Wlg + kb),
            (__attribute__((address_space(3))) void*)(&Wl[sr][sc]), 16, 0, 0);
        __builtin_amdgcn_global_load_lds(
            (const __attribute__((address_space(1))) void*)(Wlg + (size_t)64 * DIM + kb),
            (__attribute__((address_space(3))) void*)(&Wl[sr + 64][sc]), 16, 0, 0);
        __syncthreads();
        short8 af = *(const short8*)&Zs[wave * 16 + fr][fq * 8];
        #pragma unroll
        for (int ni = 0; ni < 8; ni++) {
            short8 bh = *(const short8*)&Wh[ni * 16 + fr][fq * 8];
            acc[ni] = __builtin_amdgcn_mfma_f32_16x16x32_bf16(af, bh, acc[ni], 0, 0, 0);
        }
        #pragma unroll
        for (int ni = 0; ni < 8; ni++) {
            short8 bl = *(const short8*)&Wl[ni * 16 + fr][fq * 8];
            acc[ni] = __builtin_amdgcn_mfma_f32_16x16x32_bf16(af, bl, acc[ni], 0, 0, 0);
        }
    }
    float local = 0.f;
    #pragma unroll
    for (int ni = 0; ni < 8; ni++) {
        int col = ni * 16 + fr;
        float bb = b1[col], ww = w2[col];
        #pragma unroll
        for (int r = 0; r < 4; r++)
            local += tanhf(acc[ni][r] + bb) * ww;
    }
    __shared__ float red[256];
    red[tid] = local;
    __syncthreads();
    for (int s = 128; s > 0; s >>= 1) {
        if (tid < s) red[tid] += red[tid + s];
        __syncthreads();
    }
    if (tid == 0) atomicAdd(wsum_slot, red[0]);
}

// ---------------- merged prep: feat/weight splits --------------------------
__device__ __forceinline__ void split_w_body(const float* __restrict__ W,
                                             unsigned short* __restrict__ Th,
                                             unsigned short* __restrict__ Tl,
                                             int n0, int k0, int ncols,
                                             float (*t)[33], int tid) {
    int tx = tid & 31, ty = tid >> 5;   // ty 0..7
    #pragma unroll
    for (int i = 0; i < 4; i++)
        t[ty + 8 * i][tx] = W[(size_t)(k0 + ty + 8 * i) * ncols + n0 + tx];
    __syncthreads();
    #pragma unroll
    for (int i = 0; i < 4; i++) {
        float x = t[tx][ty + 8 * i];
        unsigned short h = f2bf(x);
        size_t off = (size_t)(n0 + ty + 8 * i) * DIM + k0 + tx;
        Th[off] = h;
        Tl[off] = f2bf(x - bf2f(h));
    }
}

__global__ __launch_bounds__(256) void prep(const float* __restrict__ feat,
                                            const float* __restrict__ w1,
                                            const float* __restrict__ fcw0,
                                            const float* __restrict__ fcw1,
                                            unsigned short* __restrict__ fH,
                                            unsigned short* __restrict__ fL,
                                            unsigned short* __restrict__ W1hT,
                                            unsigned short* __restrict__ W1lT,
                                            unsigned short* __restrict__ BhT0,
                                            unsigned short* __restrict__ BlT0,
                                            unsigned short* __restrict__ BhT1,
                                            unsigned short* __restrict__ BlT1) {
    int b = blockIdx.x;
    __shared__ float t[32][33];
    if (b < 4096) {                       // split_feat over float4s
        int i = b * 256 + threadIdx.x;
        float4 v = ((const float4*)feat)[i];
        unsigned short h0 = f2bf(v.x), h1 = f2bf(v.y), h2 = f2bf(v.z), h3 = f2bf(v.w);
        ushort4 hv; hv.x = h0; hv.y = h1; hv.z = h2; hv.w = h3;
        ushort4 lv;
        lv.x = f2bf(v.x - bf2f(h0));
        lv.y = f2bf(v.y - bf2f(h1));
        lv.z = f2bf(v.z - bf2f(h2));
        lv.w = f2bf(v.w - bf2f(h3));
        ((ushort4*)fH)[i] = hv;
        ((ushort4*)fL)[i] = lv;
    } else if (b < 4160) {                // sem_w1 [512][128] -> [128][512] split
        int idx = b - 4096;
        split_w_body(w1, W1hT, W1lT, (idx & 3) * 32, (idx >> 2) * 32, 128, t, threadIdx.x);
    } else if (b < 4416) {                // fcw0 [512][512] -> [n][k] split
        int idx = b - 4160;
        split_w_body(fcw0, BhT0, BlT0, (idx & 15) * 32, (idx >> 4) * 32, DIM, t, threadIdx.x);
    } else {                              // fcw1
        int idx = b - 4416;
        split_w_body(fcw1, BhT1, BlT1, (idx & 15) * 32, (idx >> 4) * 32, DIM, t, threadIdx.x);
    }
}

// ---------------- D1: gemm c=0 (512 blocks) + scatter both (2048) ----------
// contiguous ranges: de-facto phase separation (R3 lesson: interleave starves
// the GEMM's global_load_lds behind the gather flood -> -14% total)
__global__ __launch_bounds__(256) void gemm_sc(const unsigned short* __restrict__ Ah,
                                               const unsigned short* __restrict__ Al,
                                               const unsigned short* __restrict__ Bh,
                                               const unsigned short* __restrict__ Bl,
                                               float* __restrict__ Cf,
                                               unsigned short* __restrict__ Ch,
                                               const int* __restrict__ src0,
                                               const int* __restrict__ src1,
                                               const int* __restrict__ dst0,
                                               const int* __restrict__ dst1,
                                               const float* __restrict__ trans0,
                                               const float* __restrict__ trans1,
                                               int* curF, int* curC,
                                               i32x2* __restrict__ ed,
                                               i32x4* __restrict__ ce) {
    int b = blockIdx.x;
    if (b < 512) {
        gemm_body(b, Ah, Al, Bh, Bl, Cf, Ch);
    } else {
        int sb = b - 512;
        int c = sb >> 10;
        int j = (sb & 1023) * 256 + threadIdx.x;
        scatter_body(j, c, src0, src1, dst0, dst1, trans0, trans1,
                     curF, curC, ed, ce);
    }
}

// ---------------- D2: gemm c=1 (512 blocks) + edge_dots c=0 (8192) ---------
__global__ __launch_bounds__(256) void gemm_ed(const unsigned short* __restrict__ Ah,
                                               const unsigned short* __restrict__ Al,
                                               const unsigned short* __restrict__ Bh,
                                               const unsigned short* __restrict__ Bl,
                                               float* __restrict__ Cf1,
                                               unsigned short* __restrict__ Ch1,
                                               const float* __restrict__ Cf0,
                                               const int* __restrict__ cdeg0,
                                               const i32x4* __restrict__ ce0,
                                               float* __restrict__ e0,
                                               float* __restrict__ vals0) {
    int b = blockIdx.x;
    if (b < 512) {
        gemm_body(b, Ah, Al, Bh, Bl, Cf1, Ch1);
    } else {
        edge_body(b - 512, Cf0, cdeg0, ce0, e0, vals0);
    }
}

// ---------------- D3: conv_post c=0 (2048) + edge_dots c=1 (8192) ----------
__global__ __launch_bounds__(256) void conv_ed(const int* __restrict__ degF0,
                                               const i32x2* __restrict__ ed0,
                                               const float* __restrict__ e0,
                                               const float* __restrict__ vals0,
                                               const unsigned short* __restrict__ Ch0,
                                               unsigned short* __restrict__ z0,
                                               const float* __restrict__ Cf1,
                                               const int* __restrict__ cdeg1,
                                               const i32x4* __restrict__ ce1,
                                               float* __restrict__ e1,
                                               float* __restrict__ vals1) {
    int b = blockIdx.x;
    if (b < 2048) {
        conv_body(b, degF0, ed0, e0, vals0, Ch0, z0);
    } else {
        edge_body(b - 2048, Cf1, cdeg1, ce1, e1, vals1);
    }
}

// ---------------- D4: conv_post c=1 (2048) + lin(z0) (2048) ----------------
__global__ __launch_bounds__(256) void conv_lin(const int* __restrict__ degF1,
                                                const i32x2* __restrict__ ed1,
                                                const float* __restrict__ e1,
                                                const float* __restrict__ vals1,
                                                const unsigned short* __restrict__ Ch1,
                                                unsigned short* __restrict__ z1,
                                                const unsigned short* __restrict__ z0,
                                                const float* __restrict__ lin_w,
                                                float* __restrict__ y0) {
    int b = blockIdx.x;
    if (b < 2048) {
        conv_body(b, degF1, ed1, e1, vals1, Ch1, z1);
    } else {
        lin_body(b - 2048, z0, lin_w, y0);
    }
}

// ---------------- D5: sem(z0)+sem(z1) (256) + lin(z1) (2048) + fused combine
// last-block-done protocol replaces the separate combine_out dispatch:
// every block: fence -> atomicAdd(done); the 2304th block performs the
// beta-weighted combine (all writers released their stores before their add).
__global__ __launch_bounds__(256) void sem_lin(const unsigned short* __restrict__ z0,
                                               const unsigned short* __restrict__ z1,
                                               const unsigned short* __restrict__ W1hT,
                                               const unsigned short* __restrict__ W1lT,
                                               const float* __restrict__ b1,
                                               const float* __restrict__ w2,
                                               float* __restrict__ wsum,
                                               const float* __restrict__ lin_w,
                                               float* __restrict__ y1,
                                               const float* __restrict__ y0,
                                               const float* __restrict__ lin_b,
                                               int* __restrict__ done,
                                               float* __restrict__ out) {
    int b = blockIdx.x;
    if (b < 128) {
        sem_body(b, z0, W1hT, W1lT, b1, w2, &wsum[0]);
    } else if (b < 256) {
        sem_body(b - 128, z1, W1hT, W1lT, b1, w2, &wsum[1]);
    } else {
        lin_body(b - 256, z1, lin_w, y1);
    }
    // fused combine tail
    __syncthreads();          // all waves' stores issued
    __threadfence();          // release: y1/wsum visible device-wide
    __shared__ int lastf;
    if (threadIdx.x == 0) {
        int v = atomicAdd(done, 1);
        lastf = (v == 2303) ? 1 : 0;
    }
    __syncthreads();
    if (lastf) {
        __threadfence();      // acquire side
        float w0 = wsum[0] * (1.0f / NN), w1v = wsum[1] * (1.0f / NN);
        float mx = fmaxf(w0, w1v);
        float ea = expf(w0 - mx), eb = expf(w1v - mx);
        float beta0 = ea / (ea + eb), beta1 = eb / (ea + eb);
        for (int idx = threadIdx.x; idx < NN * 3; idx += 256) {
            int o = idx % 3;
            out[idx] = beta0 * y0[idx] + beta1 * y1[idx] + lin_b[o];
        }
    }
}

// ---------------- launch ----------------
extern "C" void kernel_launch(void* const* d_in, const int* in_sizes, int n_in,
                              void* d_out, int out_size, void* d_ws, size_t ws_size,
                              hipStream_t stream) {
    const float* feat = (const float*)d_in[0];
    const int*   srcp[2]   = { (const int*)d_in[1], (const int*)d_in[4] };
    const int*   dstp[2]   = { (const int*)d_in[2], (const int*)d_in[5] };
    const float* transp[2] = { (const float*)d_in[3], (const float*)d_in[6] };
    const float* fcw[2]    = { (const float*)d_in[7], (const float*)d_in[8] };
    const float* sem_w1 = (const float*)d_in[9];
    const float* sem_b1 = (const float*)d_in[10];
    const float* sem_w2 = (const float*)d_in[11];
    const float* lin_w  = (const float*)d_in[12];
    const float* lin_b  = (const float*)d_in[13];
    float* out = (float*)d_out;

    char* ws = (char*)d_ws;
    const size_t MB = 1 << 20;
    const size_t KB = 1 << 10;
    if (ws_size < 128 * MB) return;   // harness provides 256 MB
    float*          Cf0   = (float*)(ws);                        // 16 MB
    float*          Cf1   = (float*)(ws + 16 * MB);              // 16 MB
    unsigned short* Ch0   = (unsigned short*)(ws + 32 * MB);     //  8 MB
    unsigned short* Ch1   = (unsigned short*)(ws + 40 * MB);     //  8 MB
    unsigned short* z0    = (unsigned short*)(ws + 48 * MB);     //  8 MB
    unsigned short* z1    = (unsigned short*)(ws + 56 * MB);     //  8 MB
    unsigned short* fH    = (unsigned short*)(ws + 64 * MB);     //  8 MB
    unsigned short* fL    = (unsigned short*)(ws + 72 * MB);     //  8 MB
    float*          e0    = (float*)(ws + 80 * MB);              //  4 MB
    float*          e1    = (float*)(ws + 84 * MB);              //  4 MB
    float*          vals0 = (float*)(ws + 88 * MB);              // 512 KB
    float*          vals1 = (float*)(ws + 88 * MB + 512 * KB);   // 512 KB
    i32x2*          ed    = (i32x2*)(ws + 89 * MB);              // 20 MB: [2][NN][MAXD]
    i32x4*          ce    = (i32x4*)(ws + 109 * MB);             // 16 MB: [2][NN][MAXC]
    unsigned short* BhT0  = (unsigned short*)(ws + 125 * MB);              // 512 KB
    unsigned short* BlT0  = (unsigned short*)(ws + 125 * MB + 512 * KB);   // 512 KB
    unsigned short* BhT1  = (unsigned short*)(ws + 126 * MB);              // 512 KB
    unsigned short* BlT1  = (unsigned short*)(ws + 126 * MB + 512 * KB);   // 512 KB
    unsigned short* W1hT  = (unsigned short*)(ws + 127 * MB);              // 128 KB
    unsigned short* W1lT  = (unsigned short*)(ws + 127 * MB + 128 * KB);   // 128 KB
    float*          y0    = (float*)(ws + 127 * MB + 256 * KB);  // 96 KB
    float*          y1    = (float*)(ws + 127 * MB + 384 * KB);  // 96 KB
    int*            cur   = (int*)  (ws + 127 * MB + 512 * KB);  // 128 KB: [F0,F1,C0,C1]
    float*          wsum  = (float*)(ws + 127 * MB + 640 * KB);  // 8 B
    int*            done  = (int*)  (ws + 127 * MB + 640 * KB + 8); // 4 B

    // zero degree counters + wsum + done (contiguous)
    hipMemsetAsync(cur, 0, 4 * NN * sizeof(int) + 2 * sizeof(float) + sizeof(int), stream);
    // prep: feat split (4096) + w1t (64) + fcw0/1 (512)
    prep<<<4672, 256, 0, stream>>>(feat, sem_w1, fcw[0], fcw[1],
                                   fH, fL, W1hT, W1lT, BhT0, BlT0, BhT1, BlT1);
    int* curF = cur;
    int* curC = cur + 2 * NN;
    // D1: gemm c=0 + scatter both convs (atomic counts double as degrees)
    gemm_sc<<<2560, 256, 0, stream>>>(fH, fL, BhT0, BlT0, Cf0, Ch0,
                                      srcp[0], srcp[1], dstp[0], dstp[1],
                                      transp[0], transp[1],
                                      curF, curC, ed, ce);
    // D2: gemm c=1 || edge_dots c=0
    gemm_ed<<<8704, 256, 0, stream>>>(fH, fL, BhT1, BlT1, Cf1, Ch1,
                                      Cf0, curC, ce, e0, vals0);
    // D3: conv_post c=0 || edge_dots c=1
    conv_ed<<<10240, 256, 0, stream>>>(curF, ed, e0, vals0, Ch0, z0,
                                       Cf1, curC + NN, ce + (size_t)NN * MAXC,
                                       e1, vals1);
    // D4: conv_post c=1 || lin(z0)
    conv_lin<<<4096, 256, 0, stream>>>(curF + NN, ed + (size_t)NN * MAXD,
                                       e1, vals1, Ch1, z1, z0, lin_w, y0);
    // D5: sem(z0)+sem(z1) || lin(z1) + fused last-block combine
    sem_lin<<<2304, 256, 0, stream>>>(z0, z1, W1hT, W1lT, sem_b1, sem_w2,
                                      wsum, lin_w, y1, y0, lin_b, done, out);
}

// Round 6
// 321.123 us; speedup vs baseline: 1.5418x; 1.5418x over previous
//
#include <hip/hip_runtime.h>
#include <math.h>

#define NN      8192
#define DIM     512      // IN_DIM == H*HID
#define NHEAD   8
#define HID     64
#define NE      262144
#define NE_HALF 131072
#define CMASK   (NE_HALF - 1)      // canonical edge id = j & CMASK (graph symmetric)
#define TOPK    10
#define NEGV    -9e15f
#define MAXD    160     // full-degree cap; true max deg ~60 (Binom mean 32)
#define MAXC    64      // canonical-degree cap; true max ~45 (Binom mean 16)

typedef __attribute__((ext_vector_type(8))) short short8;
typedef __attribute__((ext_vector_type(4))) float f32x4;
typedef __attribute__((ext_vector_type(2))) int i32x2;
typedef __attribute__((ext_vector_type(4))) int i32x4;

__device__ __forceinline__ float bf2f(unsigned int h) {
    return __uint_as_float(h << 16);
}
__device__ __forceinline__ unsigned short f2bf(float x) {
    unsigned int u = __float_as_uint(x);
    unsigned int r = (u + 0x7fff + ((u >> 16) & 1)) >> 16;   // RNE
    return (unsigned short)r;
}

// per-wave barrier: conv_body's LDS arrays are [4][...] wave-private slices.
// s_waitcnt lgkmcnt(0) guarantees all this wave's LDS writes retired before
// subsequent reads; wave_barrier pins compiler ordering. (correctness verified
// R3/R4; replaces __syncthreads -> decouples the 4 independent waves)
// NOTE (R4 lesson): NEVER use per-block __threadfence on gfx950 — device-scope
// fence = per-XCD L2 writeback, ~190us over 2304 blocks. Dispatch boundary is
// the cheap sync.
__device__ __forceinline__ void wavebar() {
    asm volatile("s_waitcnt lgkmcnt(0)" ::: "memory");
    __builtin_amdgcn_wave_barrier();
}

// ---------------- scatter body (fused into c=0 gemm dispatch) --------------
// fixed-stride buckets: atomicAdd result IS the degree count (no scan needed)
__device__ __forceinline__ void scatter_body(int j, int c,
                                             const int* __restrict__ src0,
                                             const int* __restrict__ src1,
                                             const int* __restrict__ dst0,
                                             const int* __restrict__ dst1,
                                             const float* __restrict__ trans0,
                                             const float* __restrict__ trans1,
                                             int* curF, int* curC,
                                             i32x2* __restrict__ ed,
                                             i32x4* __restrict__ ce) {
    const int* s = c ? src1 : src0;
    const int* dt = c ? dst1 : dst0;
    int v = s[j];
    int dv = dt[j];
    int p = atomicAdd(&curF[c * NN + v], 1);
    if (p < MAXD) {
        i32x2 pk; pk.x = j; pk.y = dv;
        ed[(size_t)(c * NN + v) * MAXD + p] = pk;
    }
    if (j < NE_HALF) {
        const float* tr = c ? trans1 : trans0;
        int q = atomicAdd(&curC[c * NN + v], 1);
        if (q < MAXC) {
            i32x4 ck;
            ck.x = j; ck.y = dv; ck.z = __float_as_int(tr[j]); ck.w = 0;
            ce[(size_t)(c * NN + v) * MAXC + q] = ck;
        }
    }
}

// ---------------- GEMM body (shared: 24 KB LDS inside) ---------------------
__device__ __forceinline__ void gemm_body(int b,
                                          const unsigned short* __restrict__ Ah,
                                          const unsigned short* __restrict__ Al,
                                          const unsigned short* __restrict__ Bh,
                                          const unsigned short* __restrict__ Bl,
                                          float* __restrict__ Cf,
                                          unsigned short* __restrict__ Ch) {
    __shared__ unsigned short Ash[128][32];   // 8 KB
    __shared__ unsigned short Asl[128][32];   // 8 KB
    __shared__ unsigned short Bsh[64][32];    // 4 KB
    __shared__ unsigned short Bsl[64][32];    // 4 KB
    const int bm = (b >> 3) * 128;
    const int bn = (b & 7) * 64;
    const int tid = threadIdx.x;
    const int lane = tid & 63;
    const int wave = tid >> 6;
    const int wm = (wave >> 1) * 64, wn = (wave & 1) * 32;
    const int fr = lane & 15, fq = lane >> 4;
    const int sr = tid >> 2, sc = (tid & 3) * 8;
    f32x4 acc[4][2] = {};
    const unsigned short* Ahg = Ah + (size_t)(bm + sr) * DIM + sc;
    const unsigned short* Alg = Al + (size_t)(bm + sr) * DIM + sc;
    const unsigned short* Bhg = Bh + (size_t)(bn + sr) * DIM + sc;   // sr<64 rows used
    const unsigned short* Blg = Bl + (size_t)(bn + sr) * DIM + sc;
    for (int kb = 0; kb < DIM; kb += 32) {
        __syncthreads();
        __builtin_amdgcn_global_load_lds(
            (const __attribute__((address_space(1))) void*)(Ahg + kb),
            (__attribute__((address_space(3))) void*)(&Ash[sr][sc]), 16, 0, 0);
        __builtin_amdgcn_global_load_lds(
            (const __attribute__((address_space(1))) void*)(Ahg + (size_t)64 * DIM + kb),
            (__attribute__((address_space(3))) void*)(&Ash[sr + 64][sc]), 16, 0, 0);
        __builtin_amdgcn_global_load_lds(
            (const __attribute__((address_space(1))) void*)(Alg + kb),
            (__attribute__((address_space(3))) void*)(&Asl[sr][sc]), 16, 0, 0);
        __builtin_amdgcn_global_load_lds(
            (const __attribute__((address_space(1))) void*)(Alg + (size_t)64 * DIM + kb),
            (__attribute__((address_space(3))) void*)(&Asl[sr + 64][sc]), 16, 0, 0);
        if (sr < 64) {
            __builtin_amdgcn_global_load_lds(
                (const __attribute__((address_space(1))) void*)(Bhg + kb),
                (__attribute__((address_space(3))) void*)(&Bsh[sr][sc]), 16, 0, 0);
            __builtin_amdgcn_global_load_lds(
                (const __attribute__((address_space(1))) void*)(Blg + kb),
                (__attribute__((address_space(3))) void*)(&Bsl[sr][sc]), 16, 0, 0);
        }
        __syncthreads();
        short8 ah[4], al[4], bh[2], bl[2];
        #pragma unroll
        for (int i = 0; i < 4; i++) {
            ah[i] = *(const short8*)&Ash[wm + i * 16 + fr][fq * 8];
            al[i] = *(const short8*)&Asl[wm + i * 16 + fr][fq * 8];
        }
        #pragma unroll
        for (int i = 0; i < 2; i++) {
            bh[i] = *(const short8*)&Bsh[wn + i * 16 + fr][fq * 8];
            bl[i] = *(const short8*)&Bsl[wn + i * 16 + fr][fq * 8];
        }
        #pragma unroll
        for (int mi = 0; mi < 4; mi++)
            #pragma unroll
            for (int ni = 0; ni < 2; ni++) {
                acc[mi][ni] = __builtin_amdgcn_mfma_f32_16x16x32_bf16(ah[mi], bh[ni], acc[mi][ni], 0, 0, 0);
                acc[mi][ni] = __builtin_amdgcn_mfma_f32_16x16x32_bf16(al[mi], bh[ni], acc[mi][ni], 0, 0, 0);
                acc[mi][ni] = __builtin_amdgcn_mfma_f32_16x16x32_bf16(ah[mi], bl[ni], acc[mi][ni], 0, 0, 0);
            }
    }
    #pragma unroll
    for (int mi = 0; mi < 4; mi++)
        #pragma unroll
        for (int ni = 0; ni < 2; ni++)
            #pragma unroll
            for (int r = 0; r < 4; r++) {
                int row = bm + wm + mi * 16 + fq * 4 + r;
                int col = bn + wn + ni * 16 + fr;
                float v = acc[mi][ni][r];
                size_t off = (size_t)row * DIM + col;
                Cf[off] = v;
                Ch[off] = f2bf(v);
            }
}

// ---------------- edge-dots body (no LDS, 4 edges in flight per wave) ------
__device__ __forceinline__ void edge_body(int n,
                                          const float* __restrict__ Cf,
                                          const int* __restrict__ cdeg,
                                          const i32x4* __restrict__ ce,
                                          float* __restrict__ e,
                                          float* __restrict__ vals) {
    int d = cdeg[n];
    if (d > MAXC) d = MAXC;
    if (d <= 0) return;
    int wave = threadIdx.x >> 6, lane = threadIdx.x & 63;
    const float4* pf = (const float4*)(Cf + (size_t)n * DIM);
    float4 f0 = pf[lane * 2], f1 = pf[lane * 2 + 1];
    const size_t s0 = (size_t)n * MAXC;
    for (int base = wave * 4; base < d; base += 16) {
        int em = d - base; if (em > 4) em = 4;
        i32x4 c[4];
        #pragma unroll
        for (int t = 0; t < 4; t++)
            c[t] = ce[s0 + base + (t < em ? t : 0)];
        float4 b0[4], b1[4];
        #pragma unroll
        for (int t = 0; t < 4; t++) {
            const float4* q = (const float4*)(Cf + (size_t)c[t].y * DIM);
            b0[t] = q[lane * 2];
            b1[t] = q[lane * 2 + 1];
        }
        float p[4];
        #pragma unroll
        for (int t = 0; t < 4; t++) {
            p[t]  = f0.x * b0[t].x + f0.y * b0[t].y + f0.z * b0[t].z + f0.w * b0[t].w;
            p[t] += f1.x * b1[t].x + f1.y * b1[t].y + f1.z * b1[t].z + f1.w * b1[t].w;
            p[t] += __shfl_xor(p[t], 1);
            p[t] += __shfl_xor(p[t], 2);
            p[t] += __shfl_xor(p[t], 4);
        }
        if ((lane & 7) == 0) {
            int h = lane >> 3;
            #pragma unroll
            for (int t = 0; t < 4; t++)
                if (t < em) e[(size_t)c[t].x * NHEAD + h] = p[t];
        }
        #pragma unroll
        for (int t = 0; t < 4; t++) {
            p[t] += __shfl_xor(p[t], 8);
            p[t] += __shfl_xor(p[t], 16);
            p[t] += __shfl_xor(p[t], 32);
        }
        if (lane == 0) {
            #pragma unroll
            for (int t = 0; t < 4; t++)
                if (t < em) vals[c[t].x] = __int_as_float(c[t].z) * p[t];
        }
    }
}

// ---------------- conv-post body (wave-per-node, ~13 KB LDS) ---------------
// all LDS arrays are [4][...] wave-private slices -> wave-level barriers
// suffice (no cross-wave sharing); decouples the 4 waves' phase progress.
__device__ __forceinline__ void conv_body(int blk,
                                          const int* __restrict__ deg,
                                          const i32x2* __restrict__ ed,
                                          const float* __restrict__ e,
                                          const float* __restrict__ vals,
                                          const unsigned short* __restrict__ fb,
                                          unsigned short* __restrict__ zb) {
    const int tid = threadIdx.x;
    const int w = tid >> 6, lane = tid & 63;
    const int n = blk * 4 + w;
    int d = deg[n];
    if (d > MAXD) d = MAXD;
    const size_t s0 = (size_t)n * MAXD;
    __shared__ int   ssrc[4][MAXD];
    __shared__ int   sjc[4][MAXD];
    __shared__ float sval[4][MAXD];
    __shared__ float svc[4][MAXD];
    __shared__ unsigned char lead[4][MAXD];
    __shared__ short sk[4][MAXD];
    __shared__ float sms[4][2][NHEAD];
    __shared__ int nkept[4];

    for (int i = lane; i < d; i += 64) {
        i32x2 pk = ed[s0 + i];
        int jc = pk.x & CMASK;
        sjc[w][i] = jc;
        ssrc[w][i] = pk.y;
        sval[w][i] = vals[jc];
    }
    wavebar();
    for (int i = lane; i < d; i += 64) {
        int c = ssrc[w][i];
        float sum = 0.f;
        bool leader = true;
        for (int k = 0; k < d; k++) {
            if (ssrc[w][k] == c) {
                sum += sval[w][k];
                if (k < i) leader = false;
            }
        }
        svc[w][i] = sum;
        lead[w][i] = leader ? 1 : 0;
    }
    wavebar();
    {
        float v[3];
        #pragma unroll
        for (int s = 0; s < 3; s++) v[s] = -1.f;
        int cnt = 0;
        #pragma unroll
        for (int s = 0; s < 3; s++) {
            int i = lane + s * 64;
            if (i < d && lead[w][i] && svc[w][i] > 0.f) { v[s] = svc[w][i]; cnt++; }
        }
        cnt += __shfl_xor(cnt, 1);  cnt += __shfl_xor(cnt, 2);
        cnt += __shfl_xor(cnt, 4);  cnt += __shfl_xor(cnt, 8);
        cnt += __shfl_xor(cnt, 16); cnt += __shfl_xor(cnt, 32);
        float thr = 0.f;
        if (cnt >= TOPK) {
            unsigned long long key = 0;
            for (int t = 0; t < TOPK; t++) {
                unsigned int bb = 0; int bs = 0;
                #pragma unroll
                for (int s = 0; s < 3; s++) {
                    if (v[s] > 0.f) {
                        unsigned int b = __float_as_uint(v[s]);
                        if (b > bb) { bb = b; bs = s; }
                    }
                }
                key = ((unsigned long long)bb << 12) | (unsigned)(lane << 3) | (unsigned)bs;
                unsigned long long o;
                o = __shfl_xor(key, 1);  if (o > key) key = o;
                o = __shfl_xor(key, 2);  if (o > key) key = o;
                o = __shfl_xor(key, 4);  if (o > key) key = o;
                o = __shfl_xor(key, 8);  if (o > key) key = o;
                o = __shfl_xor(key, 16); if (o > key) key = o;
                o = __shfl_xor(key, 32); if (o > key) key = o;
                int owner = (int)((key >> 3) & 63);
                if (owner == lane) v[key & 7] = -1.f;   // remove one instance
            }
            thr = __uint_as_float((unsigned int)(key >> 12));
        }
        int base = 0;
        for (int s = 0; s * 64 < d; s++) {
            int i = s * 64 + lane;
            bool kp = (i < d) && (svc[w][i] >= thr);
            unsigned long long m = __ballot(kp);
            int pos = base + __popcll(m & ((1ull << lane) - 1ull));
            if (kp) sk[w][pos] = (short)i;
            base += (int)__popcll(m);
        }
        if (base == 0) {                 // all masked -> uniform over all d
            for (int i = lane; i < d; i += 64) sk[w][i] = (short)i;
            if (lane == 0) nkept[w] = -d;
        } else if (lane == 0) nkept[w] = base;
    }
    wavebar();
    int nk = nkept[w];
    nk = __shfl(nk, 0);   // wave-uniform broadcast (nkept written by lane 0)
    bool uni = nk < 0;
    int dk = uni ? -nk : nk;
    if (!uni) {
        int h = lane & 7, sub = lane >> 3;
        float m = -INFINITY;
        for (int k = sub; k < dk; k += 8)
            m = fmaxf(m, e[(size_t)sjc[w][sk[w][k]] * NHEAD + h]);
        m = fmaxf(m, __shfl_xor(m, 8));
        m = fmaxf(m, __shfl_xor(m, 16));
        m = fmaxf(m, __shfl_xor(m, 32));
        float s = 0.f;
        for (int k = sub; k < dk; k += 8)
            s += expf(e[(size_t)sjc[w][sk[w][k]] * NHEAD + h] - m);
        s += __shfl_xor(s, 8);
        s += __shfl_xor(s, 16);
        s += __shfl_xor(s, 32);
        if (sub == 0) { sms[w][0][h] = m; sms[w][1][h] = 1.0f / s; }
    }
    wavebar();
    int c0 = lane * 8;
    int h = lane >> 3;
    float a0 = 0.f, a1 = 0.f, a2 = 0.f, a3 = 0.f;
    float a4 = 0.f, a5 = 0.f, a6 = 0.f, a7 = 0.f;
    if (uni) {
        for (int k = 0; k < dk; k++) {
            int ii = sk[w][k];
            uint4 v = *(const uint4*)(fb + (size_t)ssrc[w][ii] * DIM + c0);
            a0 += bf2f(v.x & 0xffffu); a1 += bf2f(v.x >> 16);
            a2 += bf2f(v.y & 0xffffu); a3 += bf2f(v.y >> 16);
            a4 += bf2f(v.z & 0xffffu); a5 += bf2f(v.z >> 16);
            a6 += bf2f(v.w & 0xffffu); a7 += bf2f(v.w >> 16);
        }
        float invd = 1.0f / (float)d;
        a0 *= invd; a1 *= invd; a2 *= invd; a3 *= invd;
        a4 *= invd; a5 *= invd; a6 *= invd; a7 *= invd;
    } else {
        float m_h = sms[w][0][h], is_h = sms[w][1][h];
        for (int kb = 0; kb < dk; kb += 8) {
            int rem = dk - kb; if (rem > 8) rem = 8;
            // one expf per lane covers (edge kb+(lane&7), head lane>>3)
            float wv = 0.f;
            {
                int t = lane & 7;
                if (t < rem) {
                    int ii = sk[w][kb + t];
                    wv = expf(e[(size_t)sjc[w][ii] * NHEAD + h] - m_h) * is_h;
                }
            }
#define AGG(j) { \
            float wgt = __shfl(wv, (lane & 56) | (j)); \
            int ii2 = sk[w][kb + (j)]; \
            uint4 vv = *(const uint4*)(fb + (size_t)ssrc[w][ii2] * DIM + c0); \
            a0 += wgt * bf2f(vv.x & 0xffffu); a1 += wgt * bf2f(vv.x >> 16); \
            a2 += wgt * bf2f(vv.y & 0xffffu); a3 += wgt * bf2f(vv.y >> 16); \
            a4 += wgt * bf2f(vv.z & 0xffffu); a5 += wgt * bf2f(vv.z >> 16); \
            a6 += wgt * bf2f(vv.w & 0xffffu); a7 += wgt * bf2f(vv.w >> 16); }
            if (rem == 8) {
                AGG(0) AGG(1) AGG(2) AGG(3) AGG(4) AGG(5) AGG(6) AGG(7)
            } else {
                for (int j = 0; j < rem; j++) AGG(j)
            }
#undef AGG
        }
    }
    a0 = a0 > 0.f ? a0 : expf(a0) - 1.f;
    a1 = a1 > 0.f ? a1 : expf(a1) - 1.f;
    a2 = a2 > 0.f ? a2 : expf(a2) - 1.f;
    a3 = a3 > 0.f ? a3 : expf(a3) - 1.f;
    a4 = a4 > 0.f ? a4 : expf(a4) - 1.f;
    a5 = a5 > 0.f ? a5 : expf(a5) - 1.f;
    a6 = a6 > 0.f ? a6 : expf(a6) - 1.f;
    a7 = a7 > 0.f ? a7 : expf(a7) - 1.f;
    uint4 o;
    o.x = (unsigned)f2bf(a0) | ((unsigned)f2bf(a1) << 16);
    o.y = (unsigned)f2bf(a2) | ((unsigned)f2bf(a3) << 16);
    o.z = (unsigned)f2bf(a4) | ((unsigned)f2bf(a5) << 16);
    o.w = (unsigned)f2bf(a6) | ((unsigned)f2bf(a7) << 16);
    *(uint4*)(zb + (size_t)n * DIM + c0) = o;
}

// ---------------- lin body: y[n][o] = z[n] @ lin_w (wave per node) ---------
__device__ __forceinline__ void lin_body(int blk,
                                         const unsigned short* __restrict__ zb,
                                         const float* __restrict__ lin_w,
                                         float* __restrict__ y) {
    int tid = threadIdx.x;
    int w = tid >> 6, lane = tid & 63;
    int n = blk * 4 + w;
    uint4 v = *(const uint4*)(zb + (size_t)n * DIM + lane * 8);
    float f[8];
    f[0] = bf2f(v.x & 0xffffu); f[1] = bf2f(v.x >> 16);
    f[2] = bf2f(v.y & 0xffffu); f[3] = bf2f(v.y >> 16);
    f[4] = bf2f(v.z & 0xffffu); f[5] = bf2f(v.z >> 16);
    f[6] = bf2f(v.w & 0xffffu); f[7] = bf2f(v.w >> 16);
    // lin_w rows for dims [lane*8, lane*8+8): 24 contiguous floats = 6 float4
    float lwv[24];
    #pragma unroll
    for (int q = 0; q < 6; q++)
        *(float4*)&lwv[q * 4] = ((const float4*)lin_w)[lane * 6 + q];
    float acc0 = 0.f, acc1 = 0.f, acc2 = 0.f;
    #pragma unroll
    for (int j = 0; j < 8; j++) {
        acc0 += f[j] * lwv[j * 3 + 0];
        acc1 += f[j] * lwv[j * 3 + 1];
        acc2 += f[j] * lwv[j * 3 + 2];
    }
    #pragma unroll
    for (int s = 1; s < 64; s <<= 1) {
        acc0 += __shfl_xor(acc0, s);
        acc1 += __shfl_xor(acc1, s);
        acc2 += __shfl_xor(acc2, s);
    }
    if (lane == 0) {
        y[n * 3 + 0] = acc0;
        y[n * 3 + 1] = acc1;
        y[n * 3 + 2] = acc2;
    }
}

// ---------------- semantic attention scores (MFMA, fused tanh epilogue) -----
__device__ __forceinline__ void sem_body(int bx,
                                         const unsigned short* __restrict__ Z,
                                         const unsigned short* __restrict__ W1hT,
                                         const unsigned short* __restrict__ W1lT,
                                         const float* __restrict__ b1,
                                         const float* __restrict__ w2,
                                         float* wsum_slot) {
    const int bm = bx * 64;
    const int tid = threadIdx.x;
    const int lane = tid & 63, wave = tid >> 6;
    const int fr = lane & 15, fq = lane >> 4;
    __shared__ unsigned short Zs[64][32];     // 4 KB
    __shared__ unsigned short Wh[128][32];    // 8 KB
    __shared__ unsigned short Wl[128][32];    // 8 KB
    const int sr = tid >> 2, sc = (tid & 3) * 8;
    f32x4 acc[8] = {};
    const unsigned short* Zg  = Z    + (size_t)(bm + sr) * DIM + sc;
    const unsigned short* Whg = W1hT + (size_t)sr * DIM + sc;
    const unsigned short* Wlg = W1lT + (size_t)sr * DIM + sc;
    for (int kb = 0; kb < DIM; kb += 32) {
        __syncthreads();
        __builtin_amdgcn_global_load_lds(
            (const __attribute__((address_space(1))) void*)(Zg + kb),
            (__attribute__((address_space(3))) void*)(&Zs[sr][sc]), 16, 0, 0);
        __builtin_amdgcn_global_load_lds(
            (const __attribute__((address_space(1))) void*)(Whg + kb),
            (__attribute__((address_space(3))) void*)(&Wh[sr][sc]), 16, 0, 0);
        __builtin_amdgcn_global_load_lds(
            (const __attribute__((address_space(1))) void*)(Whg + (size_t)64 * DIM + kb),
            (__attribute__((address_space(3))) void*)(&Wh[sr + 64][sc]), 16, 0, 0);
        __builtin_amdgcn_global_load_lds(
            (const __attribute__((address_space(1))) void*)(Wlg + kb),
            (__attribute__((address_space(3))) void*)(&Wl[sr][sc]), 16, 0, 0);
        __builtin_amdgcn_global_load_lds(
            (const __attribute__((address_space(1))) void*)(Wlg + (size_t)64 * DIM + kb),
            (__attribute__((address_space(3))) void*)(&Wl[sr + 64][sc]), 16, 0, 0);
        __syncthreads();
        short8 af = *(const short8*)&Zs[wave * 16 + fr][fq * 8];
        #pragma unroll
        for (int ni = 0; ni < 8; ni++) {
            short8 bh = *(const short8*)&Wh[ni * 16 + fr][fq * 8];
            acc[ni] = __builtin_amdgcn_mfma_f32_16x16x32_bf16(af, bh, acc[ni], 0, 0, 0);
        }
        #pragma unroll
        for (int ni = 0; ni < 8; ni++) {
            short8 bl = *(const short8*)&Wl[ni * 16 + fr][fq * 8];
            acc[ni] = __builtin_amdgcn_mfma_f32_16x16x32_bf16(af, bl, acc[ni], 0, 0, 0);
        }
    }
    float local = 0.f;
    #pragma unroll
    for (int ni = 0; ni < 8; ni++) {
        int col = ni * 16 + fr;
        float bb = b1[col], ww = w2[col];
        #pragma unroll
        for (int r = 0; r < 4; r++)
            local += tanhf(acc[ni][r] + bb) * ww;
    }
    __shared__ float red[256];
    red[tid] = local;
    __syncthreads();
    for (int s = 128; s > 0; s >>= 1) {
        if (tid < s) red[tid] += red[tid + s];
        __syncthreads();
    }
    if (tid == 0) atomicAdd(wsum_slot, red[0]);
}

// ---------------- merged prep: feat/weight splits --------------------------
__device__ __forceinline__ void split_w_body(const float* __restrict__ W,
                                             unsigned short* __restrict__ Th,
                                             unsigned short* __restrict__ Tl,
                                             int n0, int k0, int ncols,
                                             float (*t)[33], int tid) {
    int tx = tid & 31, ty = tid >> 5;   // ty 0..7
    #pragma unroll
    for (int i = 0; i < 4; i++)
        t[ty + 8 * i][tx] = W[(size_t)(k0 + ty + 8 * i) * ncols + n0 + tx];
    __syncthreads();
    #pragma unroll
    for (int i = 0; i < 4; i++) {
        float x = t[tx][ty + 8 * i];
        unsigned short h = f2bf(x);
        size_t off = (size_t)(n0 + ty + 8 * i) * DIM + k0 + tx;
        Th[off] = h;
        Tl[off] = f2bf(x - bf2f(h));
    }
}

__global__ __launch_bounds__(256) void prep(const float* __restrict__ feat,
                                            const float* __restrict__ w1,
                                            const float* __restrict__ fcw0,
                                            const float* __restrict__ fcw1,
                                            unsigned short* __restrict__ fH,
                                            unsigned short* __restrict__ fL,
                                            unsigned short* __restrict__ W1hT,
                                            unsigned short* __restrict__ W1lT,
                                            unsigned short* __restrict__ BhT0,
                                            unsigned short* __restrict__ BlT0,
                                            unsigned short* __restrict__ BhT1,
                                            unsigned short* __restrict__ BlT1) {
    int b = blockIdx.x;
    __shared__ float t[32][33];
    if (b < 4096) {                       // split_feat over float4s
        int i = b * 256 + threadIdx.x;
        float4 v = ((const float4*)feat)[i];
        unsigned short h0 = f2bf(v.x), h1 = f2bf(v.y), h2 = f2bf(v.z), h3 = f2bf(v.w);
        ushort4 hv; hv.x = h0; hv.y = h1; hv.z = h2; hv.w = h3;
        ushort4 lv;
        lv.x = f2bf(v.x - bf2f(h0));
        lv.y = f2bf(v.y - bf2f(h1));
        lv.z = f2bf(v.z - bf2f(h2));
        lv.w = f2bf(v.w - bf2f(h3));
        ((ushort4*)fH)[i] = hv;
        ((ushort4*)fL)[i] = lv;
    } else if (b < 4160) {                // sem_w1 [512][128] -> [128][512] split
        int idx = b - 4096;
        split_w_body(w1, W1hT, W1lT, (idx & 3) * 32, (idx >> 2) * 32, 128, t, threadIdx.x);
    } else if (b < 4416) {                // fcw0 [512][512] -> [n][k] split
        int idx = b - 4160;
        split_w_body(fcw0, BhT0, BlT0, (idx & 15) * 32, (idx >> 4) * 32, DIM, t, threadIdx.x);
    } else {                              // fcw1
        int idx = b - 4416;
        split_w_body(fcw1, BhT1, BlT1, (idx & 15) * 32, (idx >> 4) * 32, DIM, t, threadIdx.x);
    }
}

// ---------------- D1: gemm c=0 (512 blocks) + scatter both (2048) ----------
// contiguous ranges: de-facto phase separation (R3 lesson: interleave starves
// the GEMM's global_load_lds behind the gather flood -> -14% total)
__global__ __launch_bounds__(256) void gemm_sc(const unsigned short* __restrict__ Ah,
                                               const unsigned short* __restrict__ Al,
                                               const unsigned short* __restrict__ Bh,
                                               const unsigned short* __restrict__ Bl,
                                               float* __restrict__ Cf,
                                               unsigned short* __restrict__ Ch,
                                               const int* __restrict__ src0,
                                               const int* __restrict__ src1,
                                               const int* __restrict__ dst0,
                                               const int* __restrict__ dst1,
                                               const float* __restrict__ trans0,
                                               const float* __restrict__ trans1,
                                               int* curF, int* curC,
                                               i32x2* __restrict__ ed,
                                               i32x4* __restrict__ ce) {
    int b = blockIdx.x;
    if (b < 512) {
        gemm_body(b, Ah, Al, Bh, Bl, Cf, Ch);
    } else {
        int sb = b - 512;
        int c = sb >> 10;
        int j = (sb & 1023) * 256 + threadIdx.x;
        scatter_body(j, c, src0, src1, dst0, dst1, trans0, trans1,
                     curF, curC, ed, ce);
    }
}

// ---------------- D2: gemm c=1 (512 blocks) + edge_dots c=0 (8192) ---------
__global__ __launch_bounds__(256) void gemm_ed(const unsigned short* __restrict__ Ah,
                                               const unsigned short* __restrict__ Al,
                                               const unsigned short* __restrict__ Bh,
                                               const unsigned short* __restrict__ Bl,
                                               float* __restrict__ Cf1,
                                               unsigned short* __restrict__ Ch1,
                                               const float* __restrict__ Cf0,
                                               const int* __restrict__ cdeg0,
                                               const i32x4* __restrict__ ce0,
                                               float* __restrict__ e0,
                                               float* __restrict__ vals0) {
    int b = blockIdx.x;
    if (b < 512) {
        gemm_body(b, Ah, Al, Bh, Bl, Cf1, Ch1);
    } else {
        edge_body(b - 512, Cf0, cdeg0, ce0, e0, vals0);
    }
}

// ---------------- D3: conv_post c=0 (2048) + edge_dots c=1 (8192) ----------
__global__ __launch_bounds__(256) void conv_ed(const int* __restrict__ degF0,
                                               const i32x2* __restrict__ ed0,
                                               const float* __restrict__ e0,
                                               const float* __restrict__ vals0,
                                               const unsigned short* __restrict__ Ch0,
                                               unsigned short* __restrict__ z0,
                                               const float* __restrict__ Cf1,
                                               const int* __restrict__ cdeg1,
                                               const i32x4* __restrict__ ce1,
                                               float* __restrict__ e1,
                                               float* __restrict__ vals1) {
    int b = blockIdx.x;
    if (b < 2048) {
        conv_body(b, degF0, ed0, e0, vals0, Ch0, z0);
    } else {
        edge_body(b - 2048, Cf1, cdeg1, ce1, e1, vals1);
    }
}

// ---------------- D4: conv_post c=1 (2048) + lin(z0) (2048) ----------------
__global__ __launch_bounds__(256) void conv_lin(const int* __restrict__ degF1,
                                                const i32x2* __restrict__ ed1,
                                                const float* __restrict__ e1,
                                                const float* __restrict__ vals1,
                                                const unsigned short* __restrict__ Ch1,
                                                unsigned short* __restrict__ z1,
                                                const unsigned short* __restrict__ z0,
                                                const float* __restrict__ lin_w,
                                                float* __restrict__ y0) {
    int b = blockIdx.x;
    if (b < 2048) {
        conv_body(b, degF1, ed1, e1, vals1, Ch1, z1);
    } else {
        lin_body(b - 2048, z0, lin_w, y0);
    }
}

// ---------------- D5: sem(z0)+sem(z1) (256) + lin(z1) (2048) ---------------
__global__ __launch_bounds__(256) void sem_lin(const unsigned short* __restrict__ z0,
                                               const unsigned short* __restrict__ z1,
                                               const unsigned short* __restrict__ W1hT,
                                               const unsigned short* __restrict__ W1lT,
                                               const float* __restrict__ b1,
                                               const float* __restrict__ w2,
                                               float* __restrict__ wsum,
                                               const float* __restrict__ lin_w,
                                               float* __restrict__ y1) {
    int b = blockIdx.x;
    if (b < 128) {
        sem_body(b, z0, W1hT, W1lT, b1, w2, &wsum[0]);
    } else if (b < 256) {
        sem_body(b - 128, z1, W1hT, W1lT, b1, w2, &wsum[1]);
    } else {
        lin_body(b - 256, z1, lin_w, y1);
    }
}

// ---------------- D6: tiny beta-weighted combine ---------------------------
__global__ __launch_bounds__(256) void combine_out(const float* __restrict__ y0,
                                                   const float* __restrict__ y1,
                                                   const float* __restrict__ wsum,
                                                   const float* __restrict__ lin_b,
                                                   float* __restrict__ out) {
    int idx = blockIdx.x * 256 + threadIdx.x;   // 24576
    float w0 = wsum[0] * (1.0f / NN), w1v = wsum[1] * (1.0f / NN);
    float mx = fmaxf(w0, w1v);
    float ea = expf(w0 - mx), eb = expf(w1v - mx);
    float beta0 = ea / (ea + eb), beta1 = eb / (ea + eb);
    int o = idx % 3;
    out[idx] = beta0 * y0[idx] + beta1 * y1[idx] + lin_b[o];
}

// ---------------- launch ----------------
extern "C" void kernel_launch(void* const* d_in, const int* in_sizes, int n_in,
                              void* d_out, int out_size, void* d_ws, size_t ws_size,
                              hipStream_t stream) {
    const float* feat = (const float*)d_in[0];
    const int*   srcp[2]   = { (const int*)d_in[1], (const int*)d_in[4] };
    const int*   dstp[2]   = { (const int*)d_in[2], (const int*)d_in[5] };
    const float* transp[2] = { (const float*)d_in[3], (const float*)d_in[6] };
    const float* fcw[2]    = { (const float*)d_in[7], (const float*)d_in[8] };
    const float* sem_w1 = (const float*)d_in[9];
    const float* sem_b1 = (const float*)d_in[10];
    const float* sem_w2 = (const float*)d_in[11];
    const float* lin_w  = (const float*)d_in[12];
    const float* lin_b  = (const float*)d_in[13];
    float* out = (float*)d_out;

    char* ws = (char*)d_ws;
    const size_t MB = 1 << 20;
    const size_t KB = 1 << 10;
    if (ws_size < 128 * MB) return;   // harness provides 256 MB
    float*          Cf0   = (float*)(ws);                        // 16 MB
    float*          Cf1   = (float*)(ws + 16 * MB);              // 16 MB
    unsigned short* Ch0   = (unsigned short*)(ws + 32 * MB);     //  8 MB
    unsigned short* Ch1   = (unsigned short*)(ws + 40 * MB);     //  8 MB
    unsigned short* z0    = (unsigned short*)(ws + 48 * MB);     //  8 MB
    unsigned short* z1    = (unsigned short*)(ws + 56 * MB);     //  8 MB
    unsigned short* fH    = (unsigned short*)(ws + 64 * MB);     //  8 MB
    unsigned short* fL    = (unsigned short*)(ws + 72 * MB);     //  8 MB
    float*          e0    = (float*)(ws + 80 * MB);              //  4 MB
    float*          e1    = (float*)(ws + 84 * MB);              //  4 MB
    float*          vals0 = (float*)(ws + 88 * MB);              // 512 KB
    float*          vals1 = (float*)(ws + 88 * MB + 512 * KB);   // 512 KB
    i32x2*          ed    = (i32x2*)(ws + 89 * MB);              // 20 MB: [2][NN][MAXD]
    i32x4*          ce    = (i32x4*)(ws + 109 * MB);             // 16 MB: [2][NN][MAXC]
    unsigned short* BhT0  = (unsigned short*)(ws + 125 * MB);              // 512 KB
    unsigned short* BlT0  = (unsigned short*)(ws + 125 * MB + 512 * KB);   // 512 KB
    unsigned short* BhT1  = (unsigned short*)(ws + 126 * MB);              // 512 KB
    unsigned short* BlT1  = (unsigned short*)(ws + 126 * MB + 512 * KB);   // 512 KB
    unsigned short* W1hT  = (unsigned short*)(ws + 127 * MB);              // 128 KB
    unsigned short* W1lT  = (unsigned short*)(ws + 127 * MB + 128 * KB);   // 128 KB
    float*          y0    = (float*)(ws + 127 * MB + 256 * KB);  // 96 KB
    float*          y1    = (float*)(ws + 127 * MB + 384 * KB);  // 96 KB
    int*            cur   = (int*)  (ws + 127 * MB + 512 * KB);  // 128 KB: [F0,F1,C0,C1]
    float*          wsum  = (float*)(ws + 127 * MB + 640 * KB);  // 8 B

    // zero degree counters + wsum (contiguous)
    hipMemsetAsync(cur, 0, 4 * NN * sizeof(int) + 2 * sizeof(float), stream);
    // prep: feat split (4096) + w1t (64) + fcw0/1 (512)
    prep<<<4672, 256, 0, stream>>>(feat, sem_w1, fcw[0], fcw[1],
                                   fH, fL, W1hT, W1lT, BhT0, BlT0, BhT1, BlT1);
    int* curF = cur;
    int* curC = cur + 2 * NN;
    // D1: gemm c=0 + scatter both convs (atomic counts double as degrees)
    gemm_sc<<<2560, 256, 0, stream>>>(fH, fL, BhT0, BlT0, Cf0, Ch0,
                                      srcp[0], srcp[1], dstp[0], dstp[1],
                                      transp[0], transp[1],
                                      curF, curC, ed, ce);
    // D2: gemm c=1 || edge_dots c=0
    gemm_ed<<<8704, 256, 0, stream>>>(fH, fL, BhT1, BlT1, Cf1, Ch1,
                                      Cf0, curC, ce, e0, vals0);
    // D3: conv_post c=0 || edge_dots c=1
    conv_ed<<<10240, 256, 0, stream>>>(curF, ed, e0, vals0, Ch0, z0,
                                       Cf1, curC + NN, ce + (size_t)NN * MAXC,
                                       e1, vals1);
    // D4: conv_post c=1 || lin(z0)
    conv_lin<<<4096, 256, 0, stream>>>(curF + NN, ed + (size_t)NN * MAXD,
                                       e1, vals1, Ch1, z1, z0, lin_w, y0);
    // D5: sem(z0)+sem(z1) || lin(z1)
    sem_lin<<<2304, 256, 0, stream>>>(z0, z1, W1hT, W1lT, sem_b1, sem_w2,
                                      wsum, lin_w, y1);
    // D6: combine
    combine_out<<<(NN * 3) / 256, 256, 0, stream>>>(y0, y1, wsum, lin_b, out);
}